// Round 2
// baseline (691.497 us; speedup 1.0000x reference)
//
#include <hip/hip_runtime.h>
#include <hip/hip_bf16.h>
#include <cstdint>

#define DI __device__ __forceinline__

typedef __attribute__((ext_vector_type(8))) short v8s;   // 8 bf16 (4 VGPRs)
typedef __attribute__((ext_vector_type(4))) float v4f;   // 4 f32 acc

// ---- problem constants ----
constexpr int Bc = 2, Nc = 2048, Cc = 1024, Hc = 16, Dc = 64;

DI float bfbits(uint32_t u) { union { uint32_t i; float f; } c; c.i = u; return c.f; }
DI unsigned short f2bf(float f) {
    union { float f; uint32_t u; } c; c.f = f;
    uint32_t r = c.u + 0x7FFFu + ((c.u >> 16) & 1u);   // RNE
    return (unsigned short)(r >> 16);
}
DI void unpackb8(uint4 u, float* f) {
    f[0] = bfbits(u.x << 16); f[1] = bfbits(u.x & 0xFFFF0000u);
    f[2] = bfbits(u.y << 16); f[3] = bfbits(u.y & 0xFFFF0000u);
    f[4] = bfbits(u.z << 16); f[5] = bfbits(u.z & 0xFFFF0000u);
    f[6] = bfbits(u.w << 16); f[7] = bfbits(u.w & 0xFFFF0000u);
}
DI float gpow(float g, float p) {
    if (p <= 0.f) return 1.f;
    if (g <= 0.f) return 0.f;
    return exp2f(p * log2f(g));
}

// ---------------------------------------------------------------------------
// cvt: f32 -> bf16, 8 elems/thread
// ---------------------------------------------------------------------------
__global__ __launch_bounds__(256) void cvt_bf16(
    const float* __restrict__ in, unsigned short* __restrict__ out, int n8)
{
    int i = blockIdx.x * 256 + threadIdx.x;
    if (i >= n8) return;
    float4 a = ((const float4*)in)[i * 2];
    float4 b = ((const float4*)in)[i * 2 + 1];
    ushort4 r0; r0.x = f2bf(a.x); r0.y = f2bf(a.y); r0.z = f2bf(a.z); r0.w = f2bf(a.w);
    ushort4 r1; r1.x = f2bf(b.x); r1.y = f2bf(b.y); r1.z = f2bf(b.z); r1.w = f2bf(b.w);
    ((ushort4*)out)[i * 2] = r0; ((ushort4*)out)[i * 2 + 1] = r1;
}

// ---------------------------------------------------------------------------
// transpose + cvt: in f32 [R][C] -> out bf16 [C][R].  grid (C/64, R/64)
// ---------------------------------------------------------------------------
__global__ __launch_bounds__(256) void transpose_cvt(
    const float* __restrict__ in, unsigned short* __restrict__ out, int R, int C)
{
    __shared__ float T[64][65];
    const int tid = threadIdx.x;
    const int r0 = blockIdx.y * 64, c0 = blockIdx.x * 64;
    #pragma unroll
    for (int rep = 0; rep < 4; rep++) {
        int row = (tid >> 4) + rep * 16, col = (tid & 15) * 4;
        float4 v = *reinterpret_cast<const float4*>(in + (size_t)(r0 + row) * C + c0 + col);
        T[row][col] = v.x; T[row][col + 1] = v.y; T[row][col + 2] = v.z; T[row][col + 3] = v.w;
    }
    __syncthreads();
    #pragma unroll
    for (int rep = 0; rep < 4; rep++) {
        int ocr = (tid >> 4) + rep * 16, j4 = (tid & 15) * 4;
        ushort4 w;
        w.x = f2bf(T[j4][ocr]);     w.y = f2bf(T[j4 + 1][ocr]);
        w.z = f2bf(T[j4 + 2][ocr]); w.w = f2bf(T[j4 + 3][ocr]);
        *reinterpret_cast<ushort4*>(out + (size_t)(c0 + ocr) * R + r0 + j4) = w;
    }
}

// ---------------------------------------------------------------------------
// transpose_v: vb bf16 [BH][N][D] -> vtb bf16 [BH][D][N].  grid (N/64, B*H)
// ---------------------------------------------------------------------------
__global__ __launch_bounds__(256) void transpose_v(
    const unsigned short* __restrict__ in, unsigned short* __restrict__ out)
{
    __shared__ unsigned short T[64][72];
    const int tid = threadIdx.x;
    const int n0 = blockIdx.x * 64;
    const int bh = blockIdx.y;
    const unsigned short* src = in + ((size_t)bh * Nc + n0) * Dc;
    #pragma unroll
    for (int rep = 0; rep < 2; rep++) {
        int r = (tid >> 3) + rep * 32, c = (tid & 7) * 8;
        *(uint4*)&T[r][c] = *(const uint4*)(src + (size_t)r * Dc + c);
    }
    __syncthreads();
    unsigned short* dst = out + (size_t)bh * Dc * Nc + n0;
    #pragma unroll
    for (int rep = 0; rep < 2; rep++) {
        int d = (tid >> 3) + rep * 32, c0 = (tid & 7) * 8;
        union { uint4 u; unsigned short s[8]; } w;
        #pragma unroll
        for (int j = 0; j < 8; j++) w.s[j] = T[c0 + j][d];
        *(uint4*)(dst + (size_t)d * Nc + c0) = w.u;
    }
}

// ---------------------------------------------------------------------------
// K1: qkv GEMM, 128x128 tile, 4 waves (each 64x64). A=[4096][1024] bf16,
// Bt=[3072][1024] bf16. Scatters q(*0.125)/k/v bf16 [B,H,N,D].
// ---------------------------------------------------------------------------
__global__ __launch_bounds__(256) void qkv_mfma(
    const unsigned short* __restrict__ A, const unsigned short* __restrict__ Bt,
    const float* __restrict__ bias,
    unsigned short* __restrict__ q, unsigned short* __restrict__ k,
    unsigned short* __restrict__ v)
{
    __shared__ unsigned short As[128][72];
    __shared__ unsigned short Bs[128][72];
    const int tid = threadIdx.x, wave = tid >> 6, lane = tid & 63;
    const int L = lane & 15, quad = lane >> 4;
    const int wr = (wave >> 1) * 64, wc = (wave & 1) * 64;
    const int row0 = blockIdx.y * 128, col0 = blockIdx.x * 128;
    v4f acc[4][4];
    #pragma unroll
    for (int i = 0; i < 4; i++)
        #pragma unroll
        for (int j = 0; j < 4; j++) { acc[i][j][0]=0.f; acc[i][j][1]=0.f; acc[i][j][2]=0.f; acc[i][j][3]=0.f; }
    for (int k0 = 0; k0 < 1024; k0 += 64) {
        __syncthreads();
        #pragma unroll
        for (int rep = 0; rep < 4; rep++) {
            int r = (tid >> 3) + rep * 32, cg = (tid & 7) * 8;
            *(uint4*)&As[r][cg] = *(const uint4*)(A  + (size_t)(row0 + r) * 1024 + k0 + cg);
            *(uint4*)&Bs[r][cg] = *(const uint4*)(Bt + (size_t)(col0 + r) * 1024 + k0 + cg);
        }
        __syncthreads();
        #pragma unroll
        for (int half = 0; half < 2; half++) {
            v8s af[4], bf[4];
            #pragma unroll
            for (int s = 0; s < 4; s++) {
                af[s] = *(v8s*)&As[wr + s * 16 + L][half * 32 + quad * 8];
                bf[s] = *(v8s*)&Bs[wc + s * 16 + L][half * 32 + quad * 8];
            }
            #pragma unroll
            for (int i = 0; i < 4; i++)
                #pragma unroll
                for (int j = 0; j < 4; j++)
                    acc[i][j] = __builtin_amdgcn_mfma_f32_16x16x32_bf16(af[i], bf[j], acc[i][j], 0, 0, 0);
        }
    }
    const int which = col0 >> 10;   // block-constant (128 | 1024)
    #pragma unroll
    for (int j = 0; j < 4; j++) {
        int c = col0 + wc + j * 16 + L;
        int h = (c & 1023) >> 6, d = c & 63;
        float bv = bias[c];
        #pragma unroll
        for (int i = 0; i < 4; i++) {
            #pragma unroll
            for (int reg = 0; reg < 4; reg++) {
                int rr = row0 + wr + i * 16 + quad * 4 + reg;
                int b = rr >> 11, n = rr & 2047;
                float val = acc[i][j][reg] + bv;
                size_t base = (((size_t)(b * Hc + h)) * Nc + n) * Dc + d;
                if (which == 0)      q[base] = f2bf(val * 0.125f);
                else if (which == 1) k[base] = f2bf(val);
                else                 v[base] = f2bf(val);
            }
        }
    }
}

// ---------------------------------------------------------------------------
// K2: retention via MFMA, both batches fused per block (mask read once).
// grid (N/64, H, 2): blockIdx.z = m-chunk of 1024 (16 tiles of 64).
// chunk 0: cross term + m in [0,1024)  -> retb (bf16)
// chunk 1: m in [1024,2048)            -> pf0/pf1 (f32 partials, per batch)
// K tiles row-major from kb; V tiles row-copied from pre-transposed vtb.
// Software pipelined: next tile's K/V (8 x uint4) + mask (16 f32) prefetched
// into registers while current tile computes.
// ---------------------------------------------------------------------------
__global__ __launch_bounds__(256, 3) void retention_mfma(
    const unsigned short* __restrict__ qb, const unsigned short* __restrict__ kb,
    const unsigned short* __restrict__ vtb,
    const float* __restrict__ mask, const float* __restrict__ gamma,
    const float* __restrict__ sprev,
    unsigned short* __restrict__ retb, float* __restrict__ pf0, float* __restrict__ pf1)
{
    __shared__ unsigned short K0[64][72], K1[64][72];   // K tiles (also spT at init)
    __shared__ unsigned short V0[64][72], V1[64][72];   // V^T tiles (also Q at init)
    __shared__ unsigned short Sm[64][72];               // masked scores (per-wave bands)
    const int tid = threadIdx.x, wave = tid >> 6, lane = tid & 63;
    const int L = lane & 15, quad = lane >> 4;
    const int h = blockIdx.y;
    const int n0 = blockIdx.x * 64;
    const int chunk = blockIdx.z;
    const int m_base = chunk * 1024;
    const float g = gamma[h];
    const int bh0 = h, bh1 = Hc + h;

    {   // init stage: Q0->V0, Q1->V1 (row-major), spT0->K0, spT1->K1 (chunk0 only)
        #pragma unroll
        for (int rep = 0; rep < 2; rep++) {
            int r = (tid >> 3) + rep * 32, ch = (tid & 7) * 8;
            *(uint4*)&V0[r][ch] = *(const uint4*)(qb + ((size_t)bh0 * Nc + n0 + r) * Dc + ch);
            *(uint4*)&V1[r][ch] = *(const uint4*)(qb + ((size_t)bh1 * Nc + n0 + r) * Dc + ch);
        }
        if (chunk == 0) {
            int dd = tid >> 2, e0 = (tid & 3) * 16;
            const float* sp0 = sprev + ((size_t)bh0 * 64 + dd) * 64 + e0;
            const float* sp1 = sprev + ((size_t)bh1 * 64 + dd) * 64 + e0;
            #pragma unroll
            for (int j = 0; j < 16; j++) K0[e0 + j][dd] = f2bf(sp0[j]);
            #pragma unroll
            for (int j = 0; j < 16; j++) K1[e0 + j][dd] = f2bf(sp1[j]);
        }
    }
    __syncthreads();
    v8s qf[2][2];
    qf[0][0] = *(v8s*)&V0[wave * 16 + L][quad * 8];
    qf[0][1] = *(v8s*)&V0[wave * 16 + L][32 + quad * 8];
    qf[1][0] = *(v8s*)&V1[wave * 16 + L][quad * 8];
    qf[1][1] = *(v8s*)&V1[wave * 16 + L][32 + quad * 8];
    v4f oacc[2][4];
    if (chunk == 0) {
        #pragma unroll
        for (int b = 0; b < 2; b++) {
            unsigned short (*Kb)[72] = b ? K1 : K0;
            #pragma unroll
            for (int s = 0; s < 4; s++) {
                v4f a; a[0] = 0.f; a[1] = 0.f; a[2] = 0.f; a[3] = 0.f;
                a = __builtin_amdgcn_mfma_f32_16x16x32_bf16(qf[b][0], *(v8s*)&Kb[s * 16 + L][quad * 8], a, 0, 0, 0);
                a = __builtin_amdgcn_mfma_f32_16x16x32_bf16(qf[b][1], *(v8s*)&Kb[s * 16 + L][32 + quad * 8], a, 0, 0, 0);
                oacc[b][s] = a;
            }
        }
        // scale cross terms by gamma^(nrow+1) (same for both batches)
        float cf = gpow(g, (float)(n0 + wave * 16 + quad * 4 + 1));
        #pragma unroll
        for (int reg = 0; reg < 4; reg++) {
            #pragma unroll
            for (int b = 0; b < 2; b++)
                #pragma unroll
                for (int s = 0; s < 4; s++) oacc[b][s][reg] *= cf;
            cf *= g;
        }
    } else {
        #pragma unroll
        for (int b = 0; b < 2; b++)
            #pragma unroll
            for (int s = 0; s < 4; s++) { oacc[b][s][0]=0.f; oacc[b][s][1]=0.f; oacc[b][s][2]=0.f; oacc[b][s][3]=0.f; }
    }

    const unsigned short* kp0 = kb + (size_t)bh0 * Nc * Dc;
    const unsigned short* kp1 = kb + (size_t)bh1 * Nc * Dc;
    const unsigned short* vt0 = vtb + (size_t)bh0 * Dc * Nc;
    const unsigned short* vt1 = vtb + (size_t)bh1 * Dc * Nc;
    const float* mptr = mask + (size_t)h * Nc * Nc
                      + (size_t)(n0 + wave * 16 + quad * 4) * Nc + L;

    const int r1 = tid >> 3, ch = (tid & 7) * 8;
    uint4 pk0[2], pk1[2], pv0[2], pv1[2];
    float mv[4][4];
    {   // prologue: prefetch tile 0 into registers
        const int m0 = m_base;
        #pragma unroll
        for (int rep = 0; rep < 2; rep++) {
            int r = r1 + rep * 32;
            pk0[rep] = *(const uint4*)(kp0 + (size_t)(m0 + r) * Dc + ch);
            pk1[rep] = *(const uint4*)(kp1 + (size_t)(m0 + r) * Dc + ch);
            pv0[rep] = *(const uint4*)(vt0 + (size_t)r * Nc + m0 + ch);
            pv1[rep] = *(const uint4*)(vt1 + (size_t)r * Nc + m0 + ch);
        }
        #pragma unroll
        for (int s = 0; s < 4; s++)
            #pragma unroll
            for (int reg = 0; reg < 4; reg++)
                mv[s][reg] = mptr[(size_t)reg * Nc + m0 + s * 16];
    }

    for (int it = 0; it < 16; ++it) {
        __syncthreads();     // prior tile's LDS reads done
        #pragma unroll
        for (int rep = 0; rep < 2; rep++) {
            int r = r1 + rep * 32;
            *(uint4*)&K0[r][ch] = pk0[rep];
            *(uint4*)&K1[r][ch] = pk1[rep];
            *(uint4*)&V0[r][ch] = pv0[rep];
            *(uint4*)&V1[r][ch] = pv1[rep];
        }
        float mc[4][4];
        #pragma unroll
        for (int s = 0; s < 4; s++)
            #pragma unroll
            for (int reg = 0; reg < 4; reg++) mc[s][reg] = mv[s][reg];
        __syncthreads();     // tiles ready
        if (it < 15) {       // prefetch next tile: overlaps all of this tile's compute
            const int m0 = m_base + (it + 1) * 64;
            #pragma unroll
            for (int rep = 0; rep < 2; rep++) {
                int r = r1 + rep * 32;
                pk0[rep] = *(const uint4*)(kp0 + (size_t)(m0 + r) * Dc + ch);
                pk1[rep] = *(const uint4*)(kp1 + (size_t)(m0 + r) * Dc + ch);
                pv0[rep] = *(const uint4*)(vt0 + (size_t)r * Nc + m0 + ch);
                pv1[rep] = *(const uint4*)(vt1 + (size_t)r * Nc + m0 + ch);
            }
            #pragma unroll
            for (int s = 0; s < 4; s++)
                #pragma unroll
                for (int reg = 0; reg < 4; reg++)
                    mv[s][reg] = mptr[(size_t)reg * Nc + m0 + s * 16];
        }
        #pragma unroll
        for (int b = 0; b < 2; b++) {
            unsigned short (*Kb)[72] = b ? K1 : K0;
            unsigned short (*Vb)[72] = b ? V1 : V0;
            v4f sa[4];
            #pragma unroll
            for (int s = 0; s < 4; s++) {
                v4f a; a[0] = 0.f; a[1] = 0.f; a[2] = 0.f; a[3] = 0.f;
                a = __builtin_amdgcn_mfma_f32_16x16x32_bf16(qf[b][0], *(v8s*)&Kb[s * 16 + L][quad * 8], a, 0, 0, 0);
                a = __builtin_amdgcn_mfma_f32_16x16x32_bf16(qf[b][1], *(v8s*)&Kb[s * 16 + L][32 + quad * 8], a, 0, 0, 0);
                sa[s] = a;
            }
            #pragma unroll
            for (int s = 0; s < 4; s++)
                #pragma unroll
                for (int reg = 0; reg < 4; reg++)
                    Sm[wave * 16 + quad * 4 + reg][s * 16 + L] = f2bf(sa[s][reg] * mc[s][reg]);
            v8s af0 = *(v8s*)&Sm[wave * 16 + L][quad * 8];
            v8s af1 = *(v8s*)&Sm[wave * 16 + L][32 + quad * 8];
            #pragma unroll
            for (int s = 0; s < 4; s++) {
                oacc[b][s] = __builtin_amdgcn_mfma_f32_16x16x32_bf16(af0, *(v8s*)&Vb[s * 16 + L][quad * 8], oacc[b][s], 0, 0, 0);
                oacc[b][s] = __builtin_amdgcn_mfma_f32_16x16x32_bf16(af1, *(v8s*)&Vb[s * 16 + L][32 + quad * 8], oacc[b][s], 0, 0, 0);
            }
        }
    }
    if (chunk == 0) {
        #pragma unroll
        for (int b = 0; b < 2; b++)
            #pragma unroll
            for (int s = 0; s < 4; s++)
                #pragma unroll
                for (int reg = 0; reg < 4; reg++) {
                    int n = n0 + wave * 16 + quad * 4 + reg;
                    retb[((size_t)b * Nc + n) * Cc + h * 64 + s * 16 + L] = f2bf(oacc[b][s][reg]);
                }
    } else {
        #pragma unroll
        for (int b = 0; b < 2; b++) {
            float* pd = b ? pf1 : pf0;
            #pragma unroll
            for (int s = 0; s < 4; s++)
                #pragma unroll
                for (int reg = 0; reg < 4; reg++) {
                    int n = n0 + wave * 16 + quad * 4 + reg;
                    pd[(size_t)n * Cc + h * 64 + s * 16 + L] = oacc[b][s][reg];
                }
        }
    }
}

// ---------------------------------------------------------------------------
// add_partial: retb[bf16] += pf{0,1}[f32], 8 elems/thread.
// ---------------------------------------------------------------------------
__global__ __launch_bounds__(256) void add_partial(
    unsigned short* __restrict__ retb,
    const float* __restrict__ pf0, const float* __restrict__ pf1, int n8)
{
    int i = blockIdx.x * 256 + threadIdx.x;
    if (i >= n8) return;
    int e = i * 8;                                    // global element index in [B*N*C)
    const float* pf = (e & (1 << 21)) ? pf1 : pf0;    // N*C = 2^21 per batch
    const float4* pp = (const float4*)(pf + (e & ((1 << 21) - 1)));
    uint4 a = ((const uint4*)retb)[i];
    float fa[8]; unpackb8(a, fa);
    float4 x0 = pp[0], x1 = pp[1];
    ushort4 r0, r1;
    r0.x = f2bf(fa[0] + x0.x); r0.y = f2bf(fa[1] + x0.y);
    r0.z = f2bf(fa[2] + x0.z); r0.w = f2bf(fa[3] + x0.w);
    r1.x = f2bf(fa[4] + x1.x); r1.y = f2bf(fa[5] + x1.y);
    r1.z = f2bf(fa[6] + x1.z); r1.w = f2bf(fa[7] + x1.w);
    ((ushort4*)retb)[2 * i] = r0; ((ushort4*)retb)[2 * i + 1] = r1;
}

// ---------------------------------------------------------------------------
// K3a: partial state over n-chunk of 256: sum_n g^(2047-n) k_n^T v_n  (bf16 in)
// ---------------------------------------------------------------------------
__global__ __launch_bounds__(256) void state_partial(
    const unsigned short* __restrict__ kg, const unsigned short* __restrict__ vg,
    const float* __restrict__ gamma,
    float* __restrict__ partial)   // [8][B*H*64*64]
{
    __shared__ float Ks[64][65];
    __shared__ float Vs[64][65];
    __shared__ float wdec[64];
    const int chunk = blockIdx.x;
    const int bh = blockIdx.y;
    const int h = bh & 15;
    const int tid = threadIdx.x;
    const int d = tid >> 2;
    const int e0 = (tid & 3) * 16;
    const float g = gamma[h];
    const unsigned short* kbp = kg + (size_t)bh * Nc * Dc;
    const unsigned short* vbp = vg + (size_t)bh * Nc * Dc;
    float acc[16] = {};
    const int nStart = chunk * 256;
    for (int m0 = nStart; m0 < nStart + 256; m0 += 64) {
        __syncthreads();
        {
            uint4 u0 = *(const uint4*)(kbp + (size_t)(m0 + d) * 64 + e0);
            uint4 u1 = *(const uint4*)(kbp + (size_t)(m0 + d) * 64 + e0 + 8);
            float f[8];
            unpackb8(u0, f);
            #pragma unroll
            for (int j = 0; j < 8; j++) Ks[d][e0 + j] = f[j];
            unpackb8(u1, f);
            #pragma unroll
            for (int j = 0; j < 8; j++) Ks[d][e0 + 8 + j] = f[j];
            uint4 w0 = *(const uint4*)(vbp + (size_t)(m0 + d) * 64 + e0);
            uint4 w1 = *(const uint4*)(vbp + (size_t)(m0 + d) * 64 + e0 + 8);
            unpackb8(w0, f);
            #pragma unroll
            for (int j = 0; j < 8; j++) Vs[d][e0 + j] = f[j];
            unpackb8(w1, f);
            #pragma unroll
            for (int j = 0; j < 8; j++) Vs[d][e0 + 8 + j] = f[j];
        }
        if (tid < 64) wdec[tid] = gpow(g, (float)(2047 - (m0 + tid)));
        __syncthreads();
        for (int nn = 0; nn < 64; nn++) {
            float kw = Ks[nn][d] * wdec[nn];
            #pragma unroll
            for (int j = 0; j < 16; j++) acc[j] += kw * Vs[nn][e0 + j];
        }
    }
    float* pp = partial + (size_t)chunk * (Bc * Hc * Dc * Dc)
              + ((size_t)bh * 64 + d) * 64 + e0;
    #pragma unroll
    for (int j = 0; j < 16; j++) pp[j] = acc[j];
}

// K3b: state = sum_chunks partial + state_prev * g^N
__global__ __launch_bounds__(256) void state_reduce(
    const float* __restrict__ partial,
    const float* __restrict__ sprev,
    const float* __restrict__ gamma,
    float* __restrict__ outState)
{
    const int idx = blockIdx.x * 256 + threadIdx.x;
    const int bh = idx >> 12;
    const int h = bh & 15;
    const float g = gamma[h];
    float acc = sprev[idx] * gpow(g, 2048.f);
    #pragma unroll
    for (int c = 0; c < 8; c++) acc += partial[(size_t)c * (Bc * Hc * Dc * Dc) + idx];
    outState[idx] = acc;
}

// ---------------------------------------------------------------------------
// K4: out GEMM, 128x128 tile. A=retb [4096][1024] bf16, Bt=Wout^T bf16.
// ---------------------------------------------------------------------------
__global__ __launch_bounds__(256) void out_mfma(
    const unsigned short* __restrict__ A, const unsigned short* __restrict__ Bt,
    const float* __restrict__ bias,
    float* __restrict__ out)   // [4096][1024] f32
{
    __shared__ unsigned short As[128][72];
    __shared__ unsigned short Bs[128][72];
    const int tid = threadIdx.x, wave = tid >> 6, lane = tid & 63;
    const int L = lane & 15, quad = lane >> 4;
    const int wr = (wave >> 1) * 64, wc = (wave & 1) * 64;
    const int row0 = blockIdx.y * 128, col0 = blockIdx.x * 128;
    v4f acc[4][4];
    #pragma unroll
    for (int i = 0; i < 4; i++)
        #pragma unroll
        for (int j = 0; j < 4; j++) { acc[i][j][0]=0.f; acc[i][j][1]=0.f; acc[i][j][2]=0.f; acc[i][j][3]=0.f; }
    for (int k0 = 0; k0 < 1024; k0 += 64) {
        __syncthreads();
        #pragma unroll
        for (int rep = 0; rep < 4; rep++) {
            int r = (tid >> 3) + rep * 32, cg = (tid & 7) * 8;
            *(uint4*)&As[r][cg] = *(const uint4*)(A  + (size_t)(row0 + r) * 1024 + k0 + cg);
            *(uint4*)&Bs[r][cg] = *(const uint4*)(Bt + (size_t)(col0 + r) * 1024 + k0 + cg);
        }
        __syncthreads();
        #pragma unroll
        for (int half = 0; half < 2; half++) {
            v8s af[4], bf[4];
            #pragma unroll
            for (int s = 0; s < 4; s++) {
                af[s] = *(v8s*)&As[wr + s * 16 + L][half * 32 + quad * 8];
                bf[s] = *(v8s*)&Bs[wc + s * 16 + L][half * 32 + quad * 8];
            }
            #pragma unroll
            for (int i = 0; i < 4; i++)
                #pragma unroll
                for (int j = 0; j < 4; j++)
                    acc[i][j] = __builtin_amdgcn_mfma_f32_16x16x32_bf16(af[i], bf[j], acc[i][j], 0, 0, 0);
        }
    }
    #pragma unroll
    for (int j = 0; j < 4; j++) {
        int c = col0 + wc + j * 16 + L;
        float bv = bias[c];
        #pragma unroll
        for (int i = 0; i < 4; i++) {
            #pragma unroll
            for (int reg = 0; reg < 4; reg++) {
                int rr = row0 + wr + i * 16 + quad * 4 + reg;
                out[(size_t)rr * 1024 + c] = acc[i][j][reg] + bv;
            }
        }
    }
}

extern "C" void kernel_launch(void* const* d_in, const int* in_sizes, int n_in,
                              void* d_out, int out_size, void* d_ws, size_t ws_size,
                              hipStream_t stream) {
    (void)in_sizes; (void)n_in; (void)out_size; (void)ws_size;
    const float* x     = (const float*)d_in[0]; // [B,N,C]
    const float* mask  = (const float*)d_in[1]; // [H,N,N]
    const float* gamma = (const float*)d_in[2]; // [H]
    const float* sprev = (const float*)d_in[3]; // [B,H,D,D]
    const float* Wqkv  = (const float*)d_in[4]; // [C,3C]
    const float* bqkv  = (const float*)d_in[5]; // [3C]
    const float* Wout  = (const float*)d_in[6]; // [C,C]
    const float* bout  = (const float*)d_in[7]; // [C]

    // Workspace layout (total 60 MB, same footprint as previous version):
    //  [ 0.0, 8.4)  qb   bf16 [B,H,N,D]
    //  [ 8.4,16.8)  kb   bf16
    //  [16.8,25.2)  vb   bf16; ALIAS pf0 f32 [N,C] batch-0 partial (after state/transpose)
    //  [25.2,33.6)  retb bf16 [B,N,C]
    //  [33.6,35.7)  wot  bf16 [1024,1024]
    //  [35.7,39.8)  part f32 state partials
    //  [39.8,48.2)  xb   bf16 [4096,1024]; ALIAS vtb bf16 [B,H,D,N] (after qkv)
    //  [48.2,54.5)  wqt  bf16 [3072,1024]
    //  [54.5,62.9)  pf1  f32 [N,C] batch-1 partial
    char* W = (char*)d_ws;
    unsigned short* qb   = (unsigned short*)(W);
    unsigned short* kb   = (unsigned short*)(W + 8388608);
    unsigned short* vb   = (unsigned short*)(W + 16777216);
    float*          pf0  = (float*)        (W + 16777216);   // alias vb
    unsigned short* retb = (unsigned short*)(W + 25165824);
    unsigned short* wot  = (unsigned short*)(W + 33554432);
    float*          part = (float*)        (W + 35651584);
    unsigned short* xb   = (unsigned short*)(W + 39845888);
    unsigned short* vtb  = (unsigned short*)(W + 39845888);  // alias xb
    unsigned short* wqt  = (unsigned short*)(W + 48234496);
    float*          pf1  = (float*)        (W + 54525952);

    float* out      = (float*)d_out;                          // [B,N,C]
    float* outState = (float*)d_out + (size_t)Bc * Nc * Cc;   // [B,H,D,D]

    cvt_bf16<<<2048, 256, 0, stream>>>(x, xb, 524288);
    transpose_cvt<<<dim3(48, 16), 256, 0, stream>>>(Wqkv, wqt, 1024, 3072);
    transpose_cvt<<<dim3(16, 16), 256, 0, stream>>>(Wout, wot, 1024, 1024);
    qkv_mfma<<<dim3(24, 32), 256, 0, stream>>>(xb, wqt, bqkv, qb, kb, vb);
    transpose_v<<<dim3(32, 32), 256, 0, stream>>>(vb, vtb);       // vb -> vtb (over dead xb)
    state_partial<<<dim3(8, 32), 256, 0, stream>>>(kb, vb, gamma, part);
    state_reduce<<<512, 256, 0, stream>>>(part, sprev, gamma, outState);
    retention_mfma<<<dim3(32, 16, 2), 256, 0, stream>>>(qb, kb, vtb, mask, gamma, sprev,
                                                        retb, pf0, pf1);  // pf0 over dead vb
    add_partial<<<2048, 256, 0, stream>>>(retb, pf0, pf1, 524288);
    out_mfma<<<dim3(8, 32), 256, 0, stream>>>(retb, wot, bout, out);
}

// Round 3
// 603.986 us; speedup vs baseline: 1.1449x; 1.1449x over previous
//
#include <hip/hip_runtime.h>
#include <hip/hip_bf16.h>
#include <cstdint>

#define DI __device__ __forceinline__

typedef __attribute__((ext_vector_type(8))) short v8s;   // 8 bf16 (4 VGPRs)
typedef __attribute__((ext_vector_type(4))) float v4f;   // 4 f32 acc

// ---- problem constants ----
constexpr int Bc = 2, Nc = 2048, Cc = 1024, Hc = 16, Dc = 64;

DI float bfbits(uint32_t u) { union { uint32_t i; float f; } c; c.i = u; return c.f; }
DI unsigned short f2bf(float f) {
    union { float f; uint32_t u; } c; c.f = f;
    uint32_t r = c.u + 0x7FFFu + ((c.u >> 16) & 1u);   // RNE
    return (unsigned short)(r >> 16);
}
DI void unpackb8(uint4 u, float* f) {
    f[0] = bfbits(u.x << 16); f[1] = bfbits(u.x & 0xFFFF0000u);
    f[2] = bfbits(u.y << 16); f[3] = bfbits(u.y & 0xFFFF0000u);
    f[4] = bfbits(u.z << 16); f[5] = bfbits(u.z & 0xFFFF0000u);
    f[6] = bfbits(u.w << 16); f[7] = bfbits(u.w & 0xFFFF0000u);
}
DI float gpow(float g, float p) {
    if (p <= 0.f) return 1.f;
    if (g <= 0.f) return 0.f;
    return exp2f(p * log2f(g));
}

// ---------------------------------------------------------------------------
// cvt: f32 -> bf16, 8 elems/thread
// ---------------------------------------------------------------------------
__global__ __launch_bounds__(256) void cvt_bf16(
    const float* __restrict__ in, unsigned short* __restrict__ out, int n8)
{
    int i = blockIdx.x * 256 + threadIdx.x;
    if (i >= n8) return;
    float4 a = ((const float4*)in)[i * 2];
    float4 b = ((const float4*)in)[i * 2 + 1];
    ushort4 r0; r0.x = f2bf(a.x); r0.y = f2bf(a.y); r0.z = f2bf(a.z); r0.w = f2bf(a.w);
    ushort4 r1; r1.x = f2bf(b.x); r1.y = f2bf(b.y); r1.z = f2bf(b.z); r1.w = f2bf(b.w);
    ((ushort4*)out)[i * 2] = r0; ((ushort4*)out)[i * 2 + 1] = r1;
}

// ---------------------------------------------------------------------------
// transpose + cvt: in f32 [R][C] -> out bf16 [C][R].  grid (C/64, R/64)
// ---------------------------------------------------------------------------
__global__ __launch_bounds__(256) void transpose_cvt(
    const float* __restrict__ in, unsigned short* __restrict__ out, int R, int C)
{
    __shared__ float T[64][65];
    const int tid = threadIdx.x;
    const int r0 = blockIdx.y * 64, c0 = blockIdx.x * 64;
    #pragma unroll
    for (int rep = 0; rep < 4; rep++) {
        int row = (tid >> 4) + rep * 16, col = (tid & 15) * 4;
        float4 v = *reinterpret_cast<const float4*>(in + (size_t)(r0 + row) * C + c0 + col);
        T[row][col] = v.x; T[row][col + 1] = v.y; T[row][col + 2] = v.z; T[row][col + 3] = v.w;
    }
    __syncthreads();
    #pragma unroll
    for (int rep = 0; rep < 4; rep++) {
        int ocr = (tid >> 4) + rep * 16, j4 = (tid & 15) * 4;
        ushort4 w;
        w.x = f2bf(T[j4][ocr]);     w.y = f2bf(T[j4 + 1][ocr]);
        w.z = f2bf(T[j4 + 2][ocr]); w.w = f2bf(T[j4 + 3][ocr]);
        *reinterpret_cast<ushort4*>(out + (size_t)(c0 + ocr) * R + r0 + j4) = w;
    }
}

// ---------------------------------------------------------------------------
// transpose_v: vb bf16 [BH][N][D] -> vtb bf16 [BH][D][N].  grid (N/64, B*H)
// ---------------------------------------------------------------------------
__global__ __launch_bounds__(256) void transpose_v(
    const unsigned short* __restrict__ in, unsigned short* __restrict__ out)
{
    __shared__ unsigned short T[64][72];
    const int tid = threadIdx.x;
    const int n0 = blockIdx.x * 64;
    const int bh = blockIdx.y;
    const unsigned short* src = in + ((size_t)bh * Nc + n0) * Dc;
    #pragma unroll
    for (int rep = 0; rep < 2; rep++) {
        int r = (tid >> 3) + rep * 32, c = (tid & 7) * 8;
        *(uint4*)&T[r][c] = *(const uint4*)(src + (size_t)r * Dc + c);
    }
    __syncthreads();
    unsigned short* dst = out + (size_t)bh * Dc * Nc + n0;
    #pragma unroll
    for (int rep = 0; rep < 2; rep++) {
        int d = (tid >> 3) + rep * 32, c0 = (tid & 7) * 8;
        union { uint4 u; unsigned short s[8]; } w;
        #pragma unroll
        for (int j = 0; j < 8; j++) w.s[j] = T[c0 + j][d];
        *(uint4*)(dst + (size_t)d * Nc + c0) = w.u;
    }
}

// ---------------------------------------------------------------------------
// K1: qkv GEMM, 128x128 tile, 4 waves (each 64x64). A=[4096][1024] bf16,
// Bt=[3072][1024] bf16. Scatters q(*0.125)/k/v bf16 [B,H,N,D].
// ---------------------------------------------------------------------------
__global__ __launch_bounds__(256) void qkv_mfma(
    const unsigned short* __restrict__ A, const unsigned short* __restrict__ Bt,
    const float* __restrict__ bias,
    unsigned short* __restrict__ q, unsigned short* __restrict__ k,
    unsigned short* __restrict__ v)
{
    __shared__ unsigned short As[128][72];
    __shared__ unsigned short Bs[128][72];
    const int tid = threadIdx.x, wave = tid >> 6, lane = tid & 63;
    const int L = lane & 15, quad = lane >> 4;
    const int wr = (wave >> 1) * 64, wc = (wave & 1) * 64;
    const int row0 = blockIdx.y * 128, col0 = blockIdx.x * 128;
    v4f acc[4][4];
    #pragma unroll
    for (int i = 0; i < 4; i++)
        #pragma unroll
        for (int j = 0; j < 4; j++) { acc[i][j][0]=0.f; acc[i][j][1]=0.f; acc[i][j][2]=0.f; acc[i][j][3]=0.f; }
    for (int k0 = 0; k0 < 1024; k0 += 64) {
        __syncthreads();
        #pragma unroll
        for (int rep = 0; rep < 4; rep++) {
            int r = (tid >> 3) + rep * 32, cg = (tid & 7) * 8;
            *(uint4*)&As[r][cg] = *(const uint4*)(A  + (size_t)(row0 + r) * 1024 + k0 + cg);
            *(uint4*)&Bs[r][cg] = *(const uint4*)(Bt + (size_t)(col0 + r) * 1024 + k0 + cg);
        }
        __syncthreads();
        #pragma unroll
        for (int half = 0; half < 2; half++) {
            v8s af[4], bf[4];
            #pragma unroll
            for (int s = 0; s < 4; s++) {
                af[s] = *(v8s*)&As[wr + s * 16 + L][half * 32 + quad * 8];
                bf[s] = *(v8s*)&Bs[wc + s * 16 + L][half * 32 + quad * 8];
            }
            #pragma unroll
            for (int i = 0; i < 4; i++)
                #pragma unroll
                for (int j = 0; j < 4; j++)
                    acc[i][j] = __builtin_amdgcn_mfma_f32_16x16x32_bf16(af[i], bf[j], acc[i][j], 0, 0, 0);
        }
    }
    const int which = col0 >> 10;   // block-constant (128 | 1024)
    #pragma unroll
    for (int j = 0; j < 4; j++) {
        int c = col0 + wc + j * 16 + L;
        int h = (c & 1023) >> 6, d = c & 63;
        float bv = bias[c];
        #pragma unroll
        for (int i = 0; i < 4; i++) {
            #pragma unroll
            for (int reg = 0; reg < 4; reg++) {
                int rr = row0 + wr + i * 16 + quad * 4 + reg;
                int b = rr >> 11, n = rr & 2047;
                float val = acc[i][j][reg] + bv;
                size_t base = (((size_t)(b * Hc + h)) * Nc + n) * Dc + d;
                if (which == 0)      q[base] = f2bf(val * 0.125f);
                else if (which == 1) k[base] = f2bf(val);
                else                 v[base] = f2bf(val);
            }
        }
    }
}

// ---------------------------------------------------------------------------
// K2: retention via MFMA, both batches fused per block (mask read once).
// grid (N/64, H, 2): blockIdx.z = m-chunk of 1024 (16 tiles of 64).
// chunk 0: cross term + m in [0,1024)  -> retb (bf16)
// chunk 1: m in [1024,2048)            -> pf0/pf1 (f32 partials, per batch)
// Round-0 staging structure (direct global->LDS copies, no register
// prefetch pipeline); V staged by vectorized row-copy from pre-transposed vtb.
// ---------------------------------------------------------------------------
__global__ __launch_bounds__(256) void retention_mfma(
    const unsigned short* __restrict__ qb, const unsigned short* __restrict__ kb,
    const unsigned short* __restrict__ vtb,
    const float* __restrict__ mask, const float* __restrict__ gamma,
    const float* __restrict__ sprev,
    unsigned short* __restrict__ retb, float* __restrict__ pf0, float* __restrict__ pf1)
{
    __shared__ unsigned short K0[64][72], K1[64][72];   // K tiles (also spT at init)
    __shared__ unsigned short V0[64][72], V1[64][72];   // V^T tiles (also Q at init)
    __shared__ unsigned short Sm[64][72];               // masked scores (per-wave bands)
    const int tid = threadIdx.x, wave = tid >> 6, lane = tid & 63;
    const int L = lane & 15, quad = lane >> 4;
    const int h = blockIdx.y;
    const int n0 = blockIdx.x * 64;
    const int chunk = blockIdx.z;
    const int m_base = chunk * 1024;
    const float g = gamma[h];
    const int bh0 = h, bh1 = Hc + h;

    {   // init stage: Q0->V0, Q1->V1 (row-major), spT0->K0, spT1->K1 (chunk0 only)
        #pragma unroll
        for (int rep = 0; rep < 2; rep++) {
            int r = (tid >> 3) + rep * 32, ch = (tid & 7) * 8;
            *(uint4*)&V0[r][ch] = *(const uint4*)(qb + ((size_t)bh0 * Nc + n0 + r) * Dc + ch);
            *(uint4*)&V1[r][ch] = *(const uint4*)(qb + ((size_t)bh1 * Nc + n0 + r) * Dc + ch);
        }
        if (chunk == 0) {
            int dd = tid >> 2, e0 = (tid & 3) * 16;
            const float* sp0 = sprev + ((size_t)bh0 * 64 + dd) * 64 + e0;
            const float* sp1 = sprev + ((size_t)bh1 * 64 + dd) * 64 + e0;
            #pragma unroll
            for (int j = 0; j < 16; j++) K0[e0 + j][dd] = f2bf(sp0[j]);
            #pragma unroll
            for (int j = 0; j < 16; j++) K1[e0 + j][dd] = f2bf(sp1[j]);
        }
    }
    __syncthreads();
    v8s qf[2][2];
    qf[0][0] = *(v8s*)&V0[wave * 16 + L][quad * 8];
    qf[0][1] = *(v8s*)&V0[wave * 16 + L][32 + quad * 8];
    qf[1][0] = *(v8s*)&V1[wave * 16 + L][quad * 8];
    qf[1][1] = *(v8s*)&V1[wave * 16 + L][32 + quad * 8];
    v4f oacc[2][4];
    if (chunk == 0) {
        #pragma unroll
        for (int b = 0; b < 2; b++) {
            unsigned short (*Kb)[72] = b ? K1 : K0;
            #pragma unroll
            for (int s = 0; s < 4; s++) {
                v4f a; a[0] = 0.f; a[1] = 0.f; a[2] = 0.f; a[3] = 0.f;
                a = __builtin_amdgcn_mfma_f32_16x16x32_bf16(qf[b][0], *(v8s*)&Kb[s * 16 + L][quad * 8], a, 0, 0, 0);
                a = __builtin_amdgcn_mfma_f32_16x16x32_bf16(qf[b][1], *(v8s*)&Kb[s * 16 + L][32 + quad * 8], a, 0, 0, 0);
                oacc[b][s] = a;
            }
        }
        // scale cross terms by gamma^(nrow+1) (same for both batches)
        float cf = gpow(g, (float)(n0 + wave * 16 + quad * 4 + 1));
        #pragma unroll
        for (int reg = 0; reg < 4; reg++) {
            #pragma unroll
            for (int b = 0; b < 2; b++)
                #pragma unroll
                for (int s = 0; s < 4; s++) oacc[b][s][reg] *= cf;
            cf *= g;
        }
    } else {
        #pragma unroll
        for (int b = 0; b < 2; b++)
            #pragma unroll
            for (int s = 0; s < 4; s++) { oacc[b][s][0]=0.f; oacc[b][s][1]=0.f; oacc[b][s][2]=0.f; oacc[b][s][3]=0.f; }
    }

    const unsigned short* kp0 = kb + (size_t)bh0 * Nc * Dc;
    const unsigned short* kp1 = kb + (size_t)bh1 * Nc * Dc;
    const unsigned short* vt0 = vtb + (size_t)bh0 * Dc * Nc;
    const unsigned short* vt1 = vtb + (size_t)bh1 * Dc * Nc;
    const float* mbase = mask + (size_t)h * Nc * Nc;

    for (int it = 0; it < 16; ++it) {
        const int m0 = m_base + it * 64;
        __syncthreads();
        {   // K tiles row-major; V^T tiles row-copied from pre-transposed vtb
            #pragma unroll
            for (int rep = 0; rep < 2; rep++) {
                int r = (tid >> 3) + rep * 32, ch = (tid & 7) * 8;
                *(uint4*)&K0[r][ch] = *(const uint4*)(kp0 + (size_t)(m0 + r) * Dc + ch);
                *(uint4*)&K1[r][ch] = *(const uint4*)(kp1 + (size_t)(m0 + r) * Dc + ch);
                *(uint4*)&V0[r][ch] = *(const uint4*)(vt0 + (size_t)r * Nc + m0 + ch);
                *(uint4*)&V1[r][ch] = *(const uint4*)(vt1 + (size_t)r * Nc + m0 + ch);
            }
        }
        __syncthreads();
        // mask prefetch — shared between batches
        float mv[4][4];
        #pragma unroll
        for (int s = 0; s < 4; s++)
            #pragma unroll
            for (int reg = 0; reg < 4; reg++)
                mv[s][reg] = mbase[(size_t)(n0 + wave * 16 + quad * 4 + reg) * Nc + m0 + s * 16 + L];
        #pragma unroll
        for (int b = 0; b < 2; b++) {
            unsigned short (*Kb)[72] = b ? K1 : K0;
            unsigned short (*Vb)[72] = b ? V1 : V0;
            v4f sa[4];
            #pragma unroll
            for (int s = 0; s < 4; s++) {
                v4f a; a[0] = 0.f; a[1] = 0.f; a[2] = 0.f; a[3] = 0.f;
                a = __builtin_amdgcn_mfma_f32_16x16x32_bf16(qf[b][0], *(v8s*)&Kb[s * 16 + L][quad * 8], a, 0, 0, 0);
                a = __builtin_amdgcn_mfma_f32_16x16x32_bf16(qf[b][1], *(v8s*)&Kb[s * 16 + L][32 + quad * 8], a, 0, 0, 0);
                sa[s] = a;
            }
            #pragma unroll
            for (int s = 0; s < 4; s++)
                #pragma unroll
                for (int reg = 0; reg < 4; reg++)
                    Sm[wave * 16 + quad * 4 + reg][s * 16 + L] = f2bf(sa[s][reg] * mv[s][reg]);
            v8s af0 = *(v8s*)&Sm[wave * 16 + L][quad * 8];
            v8s af1 = *(v8s*)&Sm[wave * 16 + L][32 + quad * 8];
            #pragma unroll
            for (int s = 0; s < 4; s++) {
                oacc[b][s] = __builtin_amdgcn_mfma_f32_16x16x32_bf16(af0, *(v8s*)&Vb[s * 16 + L][quad * 8], oacc[b][s], 0, 0, 0);
                oacc[b][s] = __builtin_amdgcn_mfma_f32_16x16x32_bf16(af1, *(v8s*)&Vb[s * 16 + L][32 + quad * 8], oacc[b][s], 0, 0, 0);
            }
        }
    }
    if (chunk == 0) {
        #pragma unroll
        for (int b = 0; b < 2; b++)
            #pragma unroll
            for (int s = 0; s < 4; s++)
                #pragma unroll
                for (int reg = 0; reg < 4; reg++) {
                    int n = n0 + wave * 16 + quad * 4 + reg;
                    retb[((size_t)b * Nc + n) * Cc + h * 64 + s * 16 + L] = f2bf(oacc[b][s][reg]);
                }
    } else {
        #pragma unroll
        for (int b = 0; b < 2; b++) {
            float* pd = b ? pf1 : pf0;
            #pragma unroll
            for (int s = 0; s < 4; s++)
                #pragma unroll
                for (int reg = 0; reg < 4; reg++) {
                    int n = n0 + wave * 16 + quad * 4 + reg;
                    pd[(size_t)n * Cc + h * 64 + s * 16 + L] = oacc[b][s][reg];
                }
        }
    }
}

// ---------------------------------------------------------------------------
// add_partial: retb[bf16] += pf{0,1}[f32], 8 elems/thread.
// ---------------------------------------------------------------------------
__global__ __launch_bounds__(256) void add_partial(
    unsigned short* __restrict__ retb,
    const float* __restrict__ pf0, const float* __restrict__ pf1, int n8)
{
    int i = blockIdx.x * 256 + threadIdx.x;
    if (i >= n8) return;
    int e = i * 8;                                    // global element index in [B*N*C)
    const float* pf = (e & (1 << 21)) ? pf1 : pf0;    // N*C = 2^21 per batch
    const float4* pp = (const float4*)(pf + (e & ((1 << 21) - 1)));
    uint4 a = ((const uint4*)retb)[i];
    float fa[8]; unpackb8(a, fa);
    float4 x0 = pp[0], x1 = pp[1];
    ushort4 r0, r1;
    r0.x = f2bf(fa[0] + x0.x); r0.y = f2bf(fa[1] + x0.y);
    r0.z = f2bf(fa[2] + x0.z); r0.w = f2bf(fa[3] + x0.w);
    r1.x = f2bf(fa[4] + x1.x); r1.y = f2bf(fa[5] + x1.y);
    r1.z = f2bf(fa[6] + x1.z); r1.w = f2bf(fa[7] + x1.w);
    ((ushort4*)retb)[2 * i] = r0; ((ushort4*)retb)[2 * i + 1] = r1;
}

// ---------------------------------------------------------------------------
// K3a: partial state over n-chunk of 256: sum_n g^(2047-n) k_n^T v_n  (bf16 in)
// ---------------------------------------------------------------------------
__global__ __launch_bounds__(256) void state_partial(
    const unsigned short* __restrict__ kg, const unsigned short* __restrict__ vg,
    const float* __restrict__ gamma,
    float* __restrict__ partial)   // [8][B*H*64*64]
{
    __shared__ float Ks[64][65];
    __shared__ float Vs[64][65];
    __shared__ float wdec[64];
    const int chunk = blockIdx.x;
    const int bh = blockIdx.y;
    const int h = bh & 15;
    const int tid = threadIdx.x;
    const int d = tid >> 2;
    const int e0 = (tid & 3) * 16;
    const float g = gamma[h];
    const unsigned short* kbp = kg + (size_t)bh * Nc * Dc;
    const unsigned short* vbp = vg + (size_t)bh * Nc * Dc;
    float acc[16] = {};
    const int nStart = chunk * 256;
    for (int m0 = nStart; m0 < nStart + 256; m0 += 64) {
        __syncthreads();
        {
            uint4 u0 = *(const uint4*)(kbp + (size_t)(m0 + d) * 64 + e0);
            uint4 u1 = *(const uint4*)(kbp + (size_t)(m0 + d) * 64 + e0 + 8);
            float f[8];
            unpackb8(u0, f);
            #pragma unroll
            for (int j = 0; j < 8; j++) Ks[d][e0 + j] = f[j];
            unpackb8(u1, f);
            #pragma unroll
            for (int j = 0; j < 8; j++) Ks[d][e0 + 8 + j] = f[j];
            uint4 w0 = *(const uint4*)(vbp + (size_t)(m0 + d) * 64 + e0);
            uint4 w1 = *(const uint4*)(vbp + (size_t)(m0 + d) * 64 + e0 + 8);
            unpackb8(w0, f);
            #pragma unroll
            for (int j = 0; j < 8; j++) Vs[d][e0 + j] = f[j];
            unpackb8(w1, f);
            #pragma unroll
            for (int j = 0; j < 8; j++) Vs[d][e0 + 8 + j] = f[j];
        }
        if (tid < 64) wdec[tid] = gpow(g, (float)(2047 - (m0 + tid)));
        __syncthreads();
        for (int nn = 0; nn < 64; nn++) {
            float kw = Ks[nn][d] * wdec[nn];
            #pragma unroll
            for (int j = 0; j < 16; j++) acc[j] += kw * Vs[nn][e0 + j];
        }
    }
    float* pp = partial + (size_t)chunk * (Bc * Hc * Dc * Dc)
              + ((size_t)bh * 64 + d) * 64 + e0;
    #pragma unroll
    for (int j = 0; j < 16; j++) pp[j] = acc[j];
}

// K3b: state = sum_chunks partial + state_prev * g^N
__global__ __launch_bounds__(256) void state_reduce(
    const float* __restrict__ partial,
    const float* __restrict__ sprev,
    const float* __restrict__ gamma,
    float* __restrict__ outState)
{
    const int idx = blockIdx.x * 256 + threadIdx.x;
    const int bh = idx >> 12;
    const int h = bh & 15;
    const float g = gamma[h];
    float acc = sprev[idx] * gpow(g, 2048.f);
    #pragma unroll
    for (int c = 0; c < 8; c++) acc += partial[(size_t)c * (Bc * Hc * Dc * Dc) + idx];
    outState[idx] = acc;
}

// ---------------------------------------------------------------------------
// K4: out GEMM, 128x128 tile. A=retb [4096][1024] bf16, Bt=Wout^T bf16.
// ---------------------------------------------------------------------------
__global__ __launch_bounds__(256) void out_mfma(
    const unsigned short* __restrict__ A, const unsigned short* __restrict__ Bt,
    const float* __restrict__ bias,
    float* __restrict__ out)   // [4096][1024] f32
{
    __shared__ unsigned short As[128][72];
    __shared__ unsigned short Bs[128][72];
    const int tid = threadIdx.x, wave = tid >> 6, lane = tid & 63;
    const int L = lane & 15, quad = lane >> 4;
    const int wr = (wave >> 1) * 64, wc = (wave & 1) * 64;
    const int row0 = blockIdx.y * 128, col0 = blockIdx.x * 128;
    v4f acc[4][4];
    #pragma unroll
    for (int i = 0; i < 4; i++)
        #pragma unroll
        for (int j = 0; j < 4; j++) { acc[i][j][0]=0.f; acc[i][j][1]=0.f; acc[i][j][2]=0.f; acc[i][j][3]=0.f; }
    for (int k0 = 0; k0 < 1024; k0 += 64) {
        __syncthreads();
        #pragma unroll
        for (int rep = 0; rep < 4; rep++) {
            int r = (tid >> 3) + rep * 32, cg = (tid & 7) * 8;
            *(uint4*)&As[r][cg] = *(const uint4*)(A  + (size_t)(row0 + r) * 1024 + k0 + cg);
            *(uint4*)&Bs[r][cg] = *(const uint4*)(Bt + (size_t)(col0 + r) * 1024 + k0 + cg);
        }
        __syncthreads();
        #pragma unroll
        for (int half = 0; half < 2; half++) {
            v8s af[4], bf[4];
            #pragma unroll
            for (int s = 0; s < 4; s++) {
                af[s] = *(v8s*)&As[wr + s * 16 + L][half * 32 + quad * 8];
                bf[s] = *(v8s*)&Bs[wc + s * 16 + L][half * 32 + quad * 8];
            }
            #pragma unroll
            for (int i = 0; i < 4; i++)
                #pragma unroll
                for (int j = 0; j < 4; j++)
                    acc[i][j] = __builtin_amdgcn_mfma_f32_16x16x32_bf16(af[i], bf[j], acc[i][j], 0, 0, 0);
        }
    }
    #pragma unroll
    for (int j = 0; j < 4; j++) {
        int c = col0 + wc + j * 16 + L;
        float bv = bias[c];
        #pragma unroll
        for (int i = 0; i < 4; i++) {
            #pragma unroll
            for (int reg = 0; reg < 4; reg++) {
                int rr = row0 + wr + i * 16 + quad * 4 + reg;
                out[(size_t)rr * 1024 + c] = acc[i][j][reg] + bv;
            }
        }
    }
}

extern "C" void kernel_launch(void* const* d_in, const int* in_sizes, int n_in,
                              void* d_out, int out_size, void* d_ws, size_t ws_size,
                              hipStream_t stream) {
    (void)in_sizes; (void)n_in; (void)out_size; (void)ws_size;
    const float* x     = (const float*)d_in[0]; // [B,N,C]
    const float* mask  = (const float*)d_in[1]; // [H,N,N]
    const float* gamma = (const float*)d_in[2]; // [H]
    const float* sprev = (const float*)d_in[3]; // [B,H,D,D]
    const float* Wqkv  = (const float*)d_in[4]; // [C,3C]
    const float* bqkv  = (const float*)d_in[5]; // [3C]
    const float* Wout  = (const float*)d_in[6]; // [C,C]
    const float* bout  = (const float*)d_in[7]; // [C]

    // Workspace layout (total 60 MB):
    //  [ 0.0, 8.4)  qb   bf16 [B,H,N,D]
    //  [ 8.4,16.8)  kb   bf16
    //  [16.8,25.2)  vb   bf16; ALIAS pf0 f32 [N,C] batch-0 partial (dead after state/transpose)
    //  [25.2,33.6)  retb bf16 [B,N,C]
    //  [33.6,35.7)  wot  bf16 [1024,1024]
    //  [35.7,39.8)  part f32 state partials
    //  [39.8,48.2)  xb   bf16 [4096,1024]; ALIAS vtb bf16 [B,H,D,N] (after qkv)
    //  [48.2,54.5)  wqt  bf16 [3072,1024]
    //  [54.5,62.9)  pf1  f32 [N,C] batch-1 partial
    char* W = (char*)d_ws;
    unsigned short* qb   = (unsigned short*)(W);
    unsigned short* kb   = (unsigned short*)(W + 8388608);
    unsigned short* vb   = (unsigned short*)(W + 16777216);
    float*          pf0  = (float*)        (W + 16777216);   // alias vb
    unsigned short* retb = (unsigned short*)(W + 25165824);
    unsigned short* wot  = (unsigned short*)(W + 33554432);
    float*          part = (float*)        (W + 35651584);
    unsigned short* xb   = (unsigned short*)(W + 39845888);
    unsigned short* vtb  = (unsigned short*)(W + 39845888);  // alias xb
    unsigned short* wqt  = (unsigned short*)(W + 48234496);
    float*          pf1  = (float*)        (W + 54525952);

    float* out      = (float*)d_out;                          // [B,N,C]
    float* outState = (float*)d_out + (size_t)Bc * Nc * Cc;   // [B,H,D,D]

    cvt_bf16<<<2048, 256, 0, stream>>>(x, xb, 524288);
    transpose_cvt<<<dim3(48, 16), 256, 0, stream>>>(Wqkv, wqt, 1024, 3072);
    transpose_cvt<<<dim3(16, 16), 256, 0, stream>>>(Wout, wot, 1024, 1024);
    qkv_mfma<<<dim3(24, 32), 256, 0, stream>>>(xb, wqt, bqkv, qb, kb, vb);
    transpose_v<<<dim3(32, 32), 256, 0, stream>>>(vb, vtb);       // vb -> vtb (over dead xb)
    state_partial<<<dim3(8, 32), 256, 0, stream>>>(kb, vb, gamma, part);
    state_reduce<<<512, 256, 0, stream>>>(part, sprev, gamma, outState);
    retention_mfma<<<dim3(32, 16, 2), 256, 0, stream>>>(qb, kb, vtb, mask, gamma, sprev,
                                                        retb, pf0, pf1);  // pf0 over dead vb
    add_partial<<<2048, 256, 0, stream>>>(retb, pf0, pf1, 524288);
    out_mfma<<<dim3(8, 32), 256, 0, stream>>>(retb, wot, bout, out);
}

// Round 4
// 551.420 us; speedup vs baseline: 1.2540x; 1.0953x over previous
//
#include <hip/hip_runtime.h>
#include <hip/hip_bf16.h>
#include <cstdint>

#define DI __device__ __forceinline__

typedef __attribute__((ext_vector_type(8))) short v8s;   // 8 bf16 (4 VGPRs)
typedef __attribute__((ext_vector_type(4))) float v4f;   // 4 f32 acc

// ---- problem constants ----
constexpr int Bc = 2, Nc = 2048, Cc = 1024, Hc = 16, Dc = 64;

DI float bfbits(uint32_t u) { union { uint32_t i; float f; } c; c.i = u; return c.f; }
DI unsigned short f2bf(float f) {
    union { float f; uint32_t u; } c; c.f = f;
    uint32_t r = c.u + 0x7FFFu + ((c.u >> 16) & 1u);   // RNE
    return (unsigned short)(r >> 16);
}
DI void unpackb8(uint4 u, float* f) {
    f[0] = bfbits(u.x << 16); f[1] = bfbits(u.x & 0xFFFF0000u);
    f[2] = bfbits(u.y << 16); f[3] = bfbits(u.y & 0xFFFF0000u);
    f[4] = bfbits(u.z << 16); f[5] = bfbits(u.z & 0xFFFF0000u);
    f[6] = bfbits(u.w << 16); f[7] = bfbits(u.w & 0xFFFF0000u);
}
DI float gpow(float g, float p) {
    if (p <= 0.f) return 1.f;
    if (g <= 0.f) return 0.f;
    return exp2f(p * log2f(g));
}

// ---------------------------------------------------------------------------
// cvt: f32 -> bf16, 8 elems/thread
// ---------------------------------------------------------------------------
__global__ __launch_bounds__(256) void cvt_bf16(
    const float* __restrict__ in, unsigned short* __restrict__ out, int n8)
{
    int i = blockIdx.x * 256 + threadIdx.x;
    if (i >= n8) return;
    float4 a = ((const float4*)in)[i * 2];
    float4 b = ((const float4*)in)[i * 2 + 1];
    ushort4 r0; r0.x = f2bf(a.x); r0.y = f2bf(a.y); r0.z = f2bf(a.z); r0.w = f2bf(a.w);
    ushort4 r1; r1.x = f2bf(b.x); r1.y = f2bf(b.y); r1.z = f2bf(b.z); r1.w = f2bf(b.w);
    ((ushort4*)out)[i * 2] = r0; ((ushort4*)out)[i * 2 + 1] = r1;
}

// ---------------------------------------------------------------------------
// transpose + cvt: in f32 [R][C] -> out bf16 [C][R].  grid (C/64, R/64)
// ---------------------------------------------------------------------------
__global__ __launch_bounds__(256) void transpose_cvt(
    const float* __restrict__ in, unsigned short* __restrict__ out, int R, int C)
{
    __shared__ float T[64][65];
    const int tid = threadIdx.x;
    const int r0 = blockIdx.y * 64, c0 = blockIdx.x * 64;
    #pragma unroll
    for (int rep = 0; rep < 4; rep++) {
        int row = (tid >> 4) + rep * 16, col = (tid & 15) * 4;
        float4 v = *reinterpret_cast<const float4*>(in + (size_t)(r0 + row) * C + c0 + col);
        T[row][col] = v.x; T[row][col + 1] = v.y; T[row][col + 2] = v.z; T[row][col + 3] = v.w;
    }
    __syncthreads();
    #pragma unroll
    for (int rep = 0; rep < 4; rep++) {
        int ocr = (tid >> 4) + rep * 16, j4 = (tid & 15) * 4;
        ushort4 w;
        w.x = f2bf(T[j4][ocr]);     w.y = f2bf(T[j4 + 1][ocr]);
        w.z = f2bf(T[j4 + 2][ocr]); w.w = f2bf(T[j4 + 3][ocr]);
        *reinterpret_cast<ushort4*>(out + (size_t)(c0 + ocr) * R + r0 + j4) = w;
    }
}

// ---------------------------------------------------------------------------
// transpose_v: vb bf16 [BH][N][D] -> vtb bf16 [BH][D][N].  grid (N/64, B*H)
// ---------------------------------------------------------------------------
__global__ __launch_bounds__(256) void transpose_v(
    const unsigned short* __restrict__ in, unsigned short* __restrict__ out)
{
    __shared__ unsigned short T[64][72];
    const int tid = threadIdx.x;
    const int n0 = blockIdx.x * 64;
    const int bh = blockIdx.y;
    const unsigned short* src = in + ((size_t)bh * Nc + n0) * Dc;
    #pragma unroll
    for (int rep = 0; rep < 2; rep++) {
        int r = (tid >> 3) + rep * 32, c = (tid & 7) * 8;
        *(uint4*)&T[r][c] = *(const uint4*)(src + (size_t)r * Dc + c);
    }
    __syncthreads();
    unsigned short* dst = out + (size_t)bh * Dc * Nc + n0;
    #pragma unroll
    for (int rep = 0; rep < 2; rep++) {
        int d = (tid >> 3) + rep * 32, c0 = (tid & 7) * 8;
        union { uint4 u; unsigned short s[8]; } w;
        #pragma unroll
        for (int j = 0; j < 8; j++) w.s[j] = T[c0 + j][d];
        *(uint4*)(dst + (size_t)d * Nc + c0) = w.u;
    }
}

// ---------------------------------------------------------------------------
// K1: qkv GEMM, 128x128 tile, 4 waves (each 64x64). A=[4096][1024] bf16,
// Bt=[3072][1024] bf16. Scatters q(*0.125)/k/v bf16 [B,H,N,D].
// ---------------------------------------------------------------------------
__global__ __launch_bounds__(256) void qkv_mfma(
    const unsigned short* __restrict__ A, const unsigned short* __restrict__ Bt,
    const float* __restrict__ bias,
    unsigned short* __restrict__ q, unsigned short* __restrict__ k,
    unsigned short* __restrict__ v)
{
    __shared__ unsigned short As[128][72];
    __shared__ unsigned short Bs[128][72];
    const int tid = threadIdx.x, wave = tid >> 6, lane = tid & 63;
    const int L = lane & 15, quad = lane >> 4;
    const int wr = (wave >> 1) * 64, wc = (wave & 1) * 64;
    const int row0 = blockIdx.y * 128, col0 = blockIdx.x * 128;
    v4f acc[4][4];
    #pragma unroll
    for (int i = 0; i < 4; i++)
        #pragma unroll
        for (int j = 0; j < 4; j++) { acc[i][j][0]=0.f; acc[i][j][1]=0.f; acc[i][j][2]=0.f; acc[i][j][3]=0.f; }
    for (int k0 = 0; k0 < 1024; k0 += 64) {
        __syncthreads();
        #pragma unroll
        for (int rep = 0; rep < 4; rep++) {
            int r = (tid >> 3) + rep * 32, cg = (tid & 7) * 8;
            *(uint4*)&As[r][cg] = *(const uint4*)(A  + (size_t)(row0 + r) * 1024 + k0 + cg);
            *(uint4*)&Bs[r][cg] = *(const uint4*)(Bt + (size_t)(col0 + r) * 1024 + k0 + cg);
        }
        __syncthreads();
        #pragma unroll
        for (int half = 0; half < 2; half++) {
            v8s af[4], bf[4];
            #pragma unroll
            for (int s = 0; s < 4; s++) {
                af[s] = *(v8s*)&As[wr + s * 16 + L][half * 32 + quad * 8];
                bf[s] = *(v8s*)&Bs[wc + s * 16 + L][half * 32 + quad * 8];
            }
            #pragma unroll
            for (int i = 0; i < 4; i++)
                #pragma unroll
                for (int j = 0; j < 4; j++)
                    acc[i][j] = __builtin_amdgcn_mfma_f32_16x16x32_bf16(af[i], bf[j], acc[i][j], 0, 0, 0);
        }
    }
    const int which = col0 >> 10;   // block-constant (128 | 1024)
    #pragma unroll
    for (int j = 0; j < 4; j++) {
        int c = col0 + wc + j * 16 + L;
        int h = (c & 1023) >> 6, d = c & 63;
        float bv = bias[c];
        #pragma unroll
        for (int i = 0; i < 4; i++) {
            #pragma unroll
            for (int reg = 0; reg < 4; reg++) {
                int rr = row0 + wr + i * 16 + quad * 4 + reg;
                int b = rr >> 11, n = rr & 2047;
                float val = acc[i][j][reg] + bv;
                size_t base = (((size_t)(b * Hc + h)) * Nc + n) * Dc + d;
                if (which == 0)      q[base] = f2bf(val * 0.125f);
                else if (which == 1) k[base] = f2bf(val);
                else                 v[base] = f2bf(val);
            }
        }
    }
}

// ---------------------------------------------------------------------------
// K2: retention via MFMA. Each block: 128 n-rows, ONE batch, one m-chunk.
// grid (N/128, H, 4): blockIdx.z = batch*2 + chunk.
//   chunk 0: cross term + m in [0,1024)  -> retb (bf16)
//   chunk 1: m in [1024,2048)            -> pf0/pf1 (f32 partial for that batch)
// LDS: Kt/Vt/Sm only (27.6 KB) -> 4+ blocks/CU resident, grid exactly 4/CU.
// Per wave: 2 row-bands of 16 rows (band*64 + wave*16). Sm is per-wave-private
// rows, so no barrier needed between bands.
// ---------------------------------------------------------------------------
__global__ __launch_bounds__(256, 4) void retention_mfma(
    const unsigned short* __restrict__ qb, const unsigned short* __restrict__ kb,
    const unsigned short* __restrict__ vtb,
    const float* __restrict__ mask, const float* __restrict__ gamma,
    const float* __restrict__ sprev,
    unsigned short* __restrict__ retb, float* __restrict__ pf0, float* __restrict__ pf1)
{
    __shared__ unsigned short Kt[64][72];   // K tile row-major (also spT / Q-half at init)
    __shared__ unsigned short Vt[64][72];   // V^T tile (also Q-half at init)
    __shared__ unsigned short Sm[64][72];   // masked scores (per-wave 16-row bands)
    const int tid = threadIdx.x, wave = tid >> 6, lane = tid & 63;
    const int L = lane & 15, quad = lane >> 4;
    const int h = blockIdx.y;
    const int n0 = blockIdx.x * 128;
    const int batch = blockIdx.z >> 1;
    const int chunk = blockIdx.z & 1;
    const int m_base = chunk * 1024;
    const float g = gamma[h];
    const int bh = batch * Hc + h;

    {   // init: stage Q rows [n0,n0+64) into Kt, [n0+64,n0+128) into Vt
        #pragma unroll
        for (int rep = 0; rep < 2; rep++) {
            int r = (tid >> 3) + rep * 32, ch = (tid & 7) * 8;
            *(uint4*)&Kt[r][ch] = *(const uint4*)(qb + ((size_t)bh * Nc + n0 + r) * Dc + ch);
            *(uint4*)&Vt[r][ch] = *(const uint4*)(qb + ((size_t)bh * Nc + n0 + 64 + r) * Dc + ch);
        }
    }
    __syncthreads();
    v8s qf[2][2];   // [band][k-half]
    qf[0][0] = *(v8s*)&Kt[wave * 16 + L][quad * 8];
    qf[0][1] = *(v8s*)&Kt[wave * 16 + L][32 + quad * 8];
    qf[1][0] = *(v8s*)&Vt[wave * 16 + L][quad * 8];
    qf[1][1] = *(v8s*)&Vt[wave * 16 + L][32 + quad * 8];

    v4f oacc[2][4];
    #pragma unroll
    for (int band = 0; band < 2; band++)
        #pragma unroll
        for (int s = 0; s < 4; s++) { oacc[band][s][0]=0.f; oacc[band][s][1]=0.f; oacc[band][s][2]=0.f; oacc[band][s][3]=0.f; }

    if (chunk == 0) {   // cross term: Q @ state_prev^T-layout, scaled by gamma^(n+1)
        __syncthreads();   // qf reads done before Kt overwrite
        {
            int dd = tid >> 2, e0 = (tid & 3) * 16;
            const float* sp = sprev + ((size_t)bh * 64 + dd) * 64 + e0;
            #pragma unroll
            for (int j = 0; j < 16; j++) Kt[e0 + j][dd] = f2bf(sp[j]);
        }
        __syncthreads();
        #pragma unroll
        for (int band = 0; band < 2; band++) {
            #pragma unroll
            for (int s = 0; s < 4; s++) {
                v4f a = oacc[band][s];
                a = __builtin_amdgcn_mfma_f32_16x16x32_bf16(qf[band][0], *(v8s*)&Kt[s * 16 + L][quad * 8], a, 0, 0, 0);
                a = __builtin_amdgcn_mfma_f32_16x16x32_bf16(qf[band][1], *(v8s*)&Kt[s * 16 + L][32 + quad * 8], a, 0, 0, 0);
                oacc[band][s] = a;
            }
            float cf = gpow(g, (float)(n0 + band * 64 + wave * 16 + quad * 4 + 1));
            #pragma unroll
            for (int reg = 0; reg < 4; reg++) {
                #pragma unroll
                for (int s = 0; s < 4; s++) oacc[band][s][reg] *= cf;
                cf *= g;
            }
        }
    }

    const unsigned short* kp = kb + (size_t)bh * Nc * Dc;
    const unsigned short* vt = vtb + (size_t)bh * Dc * Nc;
    const float* mbase = mask + (size_t)h * Nc * Nc;

    for (int it = 0; it < 16; ++it) {
        const int m0 = m_base + it * 64;
        __syncthreads();
        {   // K tile row-major; V^T tile row-copied from pre-transposed vtb
            #pragma unroll
            for (int rep = 0; rep < 2; rep++) {
                int r = (tid >> 3) + rep * 32, ch = (tid & 7) * 8;
                *(uint4*)&Kt[r][ch] = *(const uint4*)(kp + (size_t)(m0 + r) * Dc + ch);
                *(uint4*)&Vt[r][ch] = *(const uint4*)(vt + (size_t)r * Nc + m0 + ch);
            }
        }
        __syncthreads();
        #pragma unroll
        for (int band = 0; band < 2; band++) {
            float mv[4][4];
            #pragma unroll
            for (int s = 0; s < 4; s++)
                #pragma unroll
                for (int reg = 0; reg < 4; reg++)
                    mv[s][reg] = mbase[(size_t)(n0 + band * 64 + wave * 16 + quad * 4 + reg) * Nc + m0 + s * 16 + L];
            v4f sa[4];
            #pragma unroll
            for (int s = 0; s < 4; s++) {
                v4f a; a[0] = 0.f; a[1] = 0.f; a[2] = 0.f; a[3] = 0.f;
                a = __builtin_amdgcn_mfma_f32_16x16x32_bf16(qf[band][0], *(v8s*)&Kt[s * 16 + L][quad * 8], a, 0, 0, 0);
                a = __builtin_amdgcn_mfma_f32_16x16x32_bf16(qf[band][1], *(v8s*)&Kt[s * 16 + L][32 + quad * 8], a, 0, 0, 0);
                sa[s] = a;
            }
            #pragma unroll
            for (int s = 0; s < 4; s++)
                #pragma unroll
                for (int reg = 0; reg < 4; reg++)
                    Sm[wave * 16 + quad * 4 + reg][s * 16 + L] = f2bf(sa[s][reg] * mv[s][reg]);
            v8s af0 = *(v8s*)&Sm[wave * 16 + L][quad * 8];
            v8s af1 = *(v8s*)&Sm[wave * 16 + L][32 + quad * 8];
            #pragma unroll
            for (int s = 0; s < 4; s++) {
                oacc[band][s] = __builtin_amdgcn_mfma_f32_16x16x32_bf16(af0, *(v8s*)&Vt[s * 16 + L][quad * 8], oacc[band][s], 0, 0, 0);
                oacc[band][s] = __builtin_amdgcn_mfma_f32_16x16x32_bf16(af1, *(v8s*)&Vt[s * 16 + L][32 + quad * 8], oacc[band][s], 0, 0, 0);
            }
        }
    }

    if (chunk == 0) {
        #pragma unroll
        for (int band = 0; band < 2; band++)
            #pragma unroll
            for (int s = 0; s < 4; s++)
                #pragma unroll
                for (int reg = 0; reg < 4; reg++) {
                    int n = n0 + band * 64 + wave * 16 + quad * 4 + reg;
                    retb[((size_t)batch * Nc + n) * Cc + h * 64 + s * 16 + L] = f2bf(oacc[band][s][reg]);
                }
    } else {
        float* pd = batch ? pf1 : pf0;
        #pragma unroll
        for (int band = 0; band < 2; band++)
            #pragma unroll
            for (int s = 0; s < 4; s++)
                #pragma unroll
                for (int reg = 0; reg < 4; reg++) {
                    int n = n0 + band * 64 + wave * 16 + quad * 4 + reg;
                    pd[(size_t)n * Cc + h * 64 + s * 16 + L] = oacc[band][s][reg];
                }
    }
}

// ---------------------------------------------------------------------------
// add_partial: retb[bf16] += pf{0,1}[f32], 8 elems/thread.
// ---------------------------------------------------------------------------
__global__ __launch_bounds__(256) void add_partial(
    unsigned short* __restrict__ retb,
    const float* __restrict__ pf0, const float* __restrict__ pf1, int n8)
{
    int i = blockIdx.x * 256 + threadIdx.x;
    if (i >= n8) return;
    int e = i * 8;                                    // global element index in [B*N*C)
    const float* pf = (e & (1 << 21)) ? pf1 : pf0;    // N*C = 2^21 per batch
    const float4* pp = (const float4*)(pf + (e & ((1 << 21) - 1)));
    uint4 a = ((const uint4*)retb)[i];
    float fa[8]; unpackb8(a, fa);
    float4 x0 = pp[0], x1 = pp[1];
    ushort4 r0, r1;
    r0.x = f2bf(fa[0] + x0.x); r0.y = f2bf(fa[1] + x0.y);
    r0.z = f2bf(fa[2] + x0.z); r0.w = f2bf(fa[3] + x0.w);
    r1.x = f2bf(fa[4] + x1.x); r1.y = f2bf(fa[5] + x1.y);
    r1.z = f2bf(fa[6] + x1.z); r1.w = f2bf(fa[7] + x1.w);
    ((ushort4*)retb)[2 * i] = r0; ((ushort4*)retb)[2 * i + 1] = r1;
}

// ---------------------------------------------------------------------------
// K3a: partial state over n-chunk of 256: sum_n g^(2047-n) k_n^T v_n  (bf16 in)
// ---------------------------------------------------------------------------
__global__ __launch_bounds__(256) void state_partial(
    const unsigned short* __restrict__ kg, const unsigned short* __restrict__ vg,
    const float* __restrict__ gamma,
    float* __restrict__ partial)   // [8][B*H*64*64]
{
    __shared__ float Ks[64][65];
    __shared__ float Vs[64][65];
    __shared__ float wdec[64];
    const int chunk = blockIdx.x;
    const int bh = blockIdx.y;
    const int h = bh & 15;
    const int tid = threadIdx.x;
    const int d = tid >> 2;
    const int e0 = (tid & 3) * 16;
    const float g = gamma[h];
    const unsigned short* kbp = kg + (size_t)bh * Nc * Dc;
    const unsigned short* vbp = vg + (size_t)bh * Nc * Dc;
    float acc[16] = {};
    const int nStart = chunk * 256;
    for (int m0 = nStart; m0 < nStart + 256; m0 += 64) {
        __syncthreads();
        {
            uint4 u0 = *(const uint4*)(kbp + (size_t)(m0 + d) * 64 + e0);
            uint4 u1 = *(const uint4*)(kbp + (size_t)(m0 + d) * 64 + e0 + 8);
            float f[8];
            unpackb8(u0, f);
            #pragma unroll
            for (int j = 0; j < 8; j++) Ks[d][e0 + j] = f[j];
            unpackb8(u1, f);
            #pragma unroll
            for (int j = 0; j < 8; j++) Ks[d][e0 + 8 + j] = f[j];
            uint4 w0 = *(const uint4*)(vbp + (size_t)(m0 + d) * 64 + e0);
            uint4 w1 = *(const uint4*)(vbp + (size_t)(m0 + d) * 64 + e0 + 8);
            unpackb8(w0, f);
            #pragma unroll
            for (int j = 0; j < 8; j++) Vs[d][e0 + j] = f[j];
            unpackb8(w1, f);
            #pragma unroll
            for (int j = 0; j < 8; j++) Vs[d][e0 + 8 + j] = f[j];
        }
        if (tid < 64) wdec[tid] = gpow(g, (float)(2047 - (m0 + tid)));
        __syncthreads();
        for (int nn = 0; nn < 64; nn++) {
            float kw = Ks[nn][d] * wdec[nn];
            #pragma unroll
            for (int j = 0; j < 16; j++) acc[j] += kw * Vs[nn][e0 + j];
        }
    }
    float* pp = partial + (size_t)chunk * (Bc * Hc * Dc * Dc)
              + ((size_t)bh * 64 + d) * 64 + e0;
    #pragma unroll
    for (int j = 0; j < 16; j++) pp[j] = acc[j];
}

// K3b: state = sum_chunks partial + state_prev * g^N
__global__ __launch_bounds__(256) void state_reduce(
    const float* __restrict__ partial,
    const float* __restrict__ sprev,
    const float* __restrict__ gamma,
    float* __restrict__ outState)
{
    const int idx = blockIdx.x * 256 + threadIdx.x;
    const int bh = idx >> 12;
    const int h = bh & 15;
    const float g = gamma[h];
    float acc = sprev[idx] * gpow(g, 2048.f);
    #pragma unroll
    for (int c = 0; c < 8; c++) acc += partial[(size_t)c * (Bc * Hc * Dc * Dc) + idx];
    outState[idx] = acc;
}

// ---------------------------------------------------------------------------
// K4: out GEMM, 128x128 tile. A=retb [4096][1024] bf16, Bt=Wout^T bf16.
// ---------------------------------------------------------------------------
__global__ __launch_bounds__(256) void out_mfma(
    const unsigned short* __restrict__ A, const unsigned short* __restrict__ Bt,
    const float* __restrict__ bias,
    float* __restrict__ out)   // [4096][1024] f32
{
    __shared__ unsigned short As[128][72];
    __shared__ unsigned short Bs[128][72];
    const int tid = threadIdx.x, wave = tid >> 6, lane = tid & 63;
    const int L = lane & 15, quad = lane >> 4;
    const int wr = (wave >> 1) * 64, wc = (wave & 1) * 64;
    const int row0 = blockIdx.y * 128, col0 = blockIdx.x * 128;
    v4f acc[4][4];
    #pragma unroll
    for (int i = 0; i < 4; i++)
        #pragma unroll
        for (int j = 0; j < 4; j++) { acc[i][j][0]=0.f; acc[i][j][1]=0.f; acc[i][j][2]=0.f; acc[i][j][3]=0.f; }
    for (int k0 = 0; k0 < 1024; k0 += 64) {
        __syncthreads();
        #pragma unroll
        for (int rep = 0; rep < 4; rep++) {
            int r = (tid >> 3) + rep * 32, cg = (tid & 7) * 8;
            *(uint4*)&As[r][cg] = *(const uint4*)(A  + (size_t)(row0 + r) * 1024 + k0 + cg);
            *(uint4*)&Bs[r][cg] = *(const uint4*)(Bt + (size_t)(col0 + r) * 1024 + k0 + cg);
        }
        __syncthreads();
        #pragma unroll
        for (int half = 0; half < 2; half++) {
            v8s af[4], bf[4];
            #pragma unroll
            for (int s = 0; s < 4; s++) {
                af[s] = *(v8s*)&As[wr + s * 16 + L][half * 32 + quad * 8];
                bf[s] = *(v8s*)&Bs[wc + s * 16 + L][half * 32 + quad * 8];
            }
            #pragma unroll
            for (int i = 0; i < 4; i++)
                #pragma unroll
                for (int j = 0; j < 4; j++)
                    acc[i][j] = __builtin_amdgcn_mfma_f32_16x16x32_bf16(af[i], bf[j], acc[i][j], 0, 0, 0);
        }
    }
    #pragma unroll
    for (int j = 0; j < 4; j++) {
        int c = col0 + wc + j * 16 + L;
        float bv = bias[c];
        #pragma unroll
        for (int i = 0; i < 4; i++) {
            #pragma unroll
            for (int reg = 0; reg < 4; reg++) {
                int rr = row0 + wr + i * 16 + quad * 4 + reg;
                out[(size_t)rr * 1024 + c] = acc[i][j][reg] + bv;
            }
        }
    }
}

extern "C" void kernel_launch(void* const* d_in, const int* in_sizes, int n_in,
                              void* d_out, int out_size, void* d_ws, size_t ws_size,
                              hipStream_t stream) {
    (void)in_sizes; (void)n_in; (void)out_size; (void)ws_size;
    const float* x     = (const float*)d_in[0]; // [B,N,C]
    const float* mask  = (const float*)d_in[1]; // [H,N,N]
    const float* gamma = (const float*)d_in[2]; // [H]
    const float* sprev = (const float*)d_in[3]; // [B,H,D,D]
    const float* Wqkv  = (const float*)d_in[4]; // [C,3C]
    const float* bqkv  = (const float*)d_in[5]; // [3C]
    const float* Wout  = (const float*)d_in[6]; // [C,C]
    const float* bout  = (const float*)d_in[7]; // [C]

    // Workspace layout (total 60 MB):
    //  [ 0.0, 8.4)  qb   bf16 [B,H,N,D]
    //  [ 8.4,16.8)  kb   bf16
    //  [16.8,25.2)  vb   bf16; ALIAS pf0 f32 [N,C] batch-0 partial (dead after state/transpose)
    //  [25.2,33.6)  retb bf16 [B,N,C]
    //  [33.6,35.7)  wot  bf16 [1024,1024]
    //  [35.7,39.8)  part f32 state partials
    //  [39.8,48.2)  xb   bf16 [4096,1024]; ALIAS vtb bf16 [B,H,D,N] (after qkv)
    //  [48.2,54.5)  wqt  bf16 [3072,1024]
    //  [54.5,62.9)  pf1  f32 [N,C] batch-1 partial
    char* W = (char*)d_ws;
    unsigned short* qb   = (unsigned short*)(W);
    unsigned short* kb   = (unsigned short*)(W + 8388608);
    unsigned short* vb   = (unsigned short*)(W + 16777216);
    float*          pf0  = (float*)        (W + 16777216);   // alias vb
    unsigned short* retb = (unsigned short*)(W + 25165824);
    unsigned short* wot  = (unsigned short*)(W + 33554432);
    float*          part = (float*)        (W + 35651584);
    unsigned short* xb   = (unsigned short*)(W + 39845888);
    unsigned short* vtb  = (unsigned short*)(W + 39845888);  // alias xb
    unsigned short* wqt  = (unsigned short*)(W + 48234496);
    float*          pf1  = (float*)        (W + 54525952);

    float* out      = (float*)d_out;                          // [B,N,C]
    float* outState = (float*)d_out + (size_t)Bc * Nc * Cc;   // [B,H,D,D]

    cvt_bf16<<<2048, 256, 0, stream>>>(x, xb, 524288);
    transpose_cvt<<<dim3(48, 16), 256, 0, stream>>>(Wqkv, wqt, 1024, 3072);
    transpose_cvt<<<dim3(16, 16), 256, 0, stream>>>(Wout, wot, 1024, 1024);
    qkv_mfma<<<dim3(24, 32), 256, 0, stream>>>(xb, wqt, bqkv, qb, kb, vb);
    transpose_v<<<dim3(32, 32), 256, 0, stream>>>(vb, vtb);       // vb -> vtb (over dead xb)
    state_partial<<<dim3(8, 32), 256, 0, stream>>>(kb, vb, gamma, part);
    state_reduce<<<512, 256, 0, stream>>>(part, sprev, gamma, outState);
    retention_mfma<<<dim3(16, 16, 4), 256, 0, stream>>>(qb, kb, vtb, mask, gamma, sprev,
                                                        retb, pf0, pf1);  // pf0 over dead vb
    add_partial<<<2048, 256, 0, stream>>>(retb, pf0, pf1, 524288);
    out_mfma<<<dim3(8, 32), 256, 0, stream>>>(retb, wot, bout, out);
}